// Round 5
// baseline (176.470 us; speedup 1.0000x reference)
//
#include <hip/hip_runtime.h>
#include <math.h>

#define NCAM 6
#define BSZ 2
#define SQL 1024
#define SKL 1680
#define NHEAD 4
#define DHEAD 32
// 1/sqrt(32) * log2(e)  (folded into Q so softmax uses exp2 directly)
#define QSCALE 0.25503494f

typedef unsigned short ushort_t;
typedef unsigned int uint_t;
typedef __attribute__((ext_vector_type(8))) short short8;   // 8 bf16
typedef __attribute__((ext_vector_type(4))) float f32x4;    // MFMA C/D frag
typedef __attribute__((ext_vector_type(4))) uint_t uint4v;  // 4 packed bf16x2

#define MFMA16 __builtin_amdgcn_mfma_f32_16x16x32_bf16

__device__ __forceinline__ ushort_t f2bf(float x) {
  uint_t u = __builtin_bit_cast(uint_t, x);
  u += 0x7FFFu + ((u >> 16) & 1u);   // RNE
  return (ushort_t)(u >> 16);
}

// pack two f32 -> (bf16(e0) | bf16(e1)<<16), truncation (same numerics as prior rounds)
__device__ __forceinline__ uint_t pk2(float e0, float e1) {
  return __builtin_amdgcn_perm(__builtin_bit_cast(uint_t, e1), __builtin_bit_cast(uint_t, e0), 0x07060302u);
}

// exact-grade GELU: erf via Abramowitz-Stegun 7.1.26 (|err|<=1.5e-7)
__device__ __forceinline__ float fast_gelu(float x) {
  const float ax = fabsf(x) * 0.70710678118654752f;
  const float tt = __builtin_amdgcn_rcpf(fmaf(0.3275911f, ax, 1.f));
  float poly = fmaf(tt, 1.061405429f, -1.453152027f);
  poly = fmaf(tt, poly, 1.421413741f);
  poly = fmaf(tt, poly, -0.284496736f);
  poly = fmaf(tt, poly, 0.254829592f);
  poly *= tt;
  const float e = __builtin_amdgcn_exp2f(-ax * ax * 1.4426950408889634f);
  float er = fmaf(-poly, e, 1.f);
  er = copysignf(er, x);
  return 0.5f * x * (1.f + er);
}

// ---------------------------------------------------------------------------
// prep: fold LN gains into transposed bf16 weights.
// Loads batched 8-wide so 8 global loads are in flight (confirmed win, R4).
// ---------------------------------------------------------------------------
__global__ __launch_bounds__(256) void prep_kernel(
    const float* __restrict__ Wq, const float* __restrict__ qg, const float* __restrict__ qb, const float* __restrict__ bq,
    const float* __restrict__ Wk, const float* __restrict__ kg, const float* __restrict__ kbb, const float* __restrict__ bk,
    const float* __restrict__ Wv, const float* __restrict__ vg, const float* __restrict__ vbb, const float* __restrict__ bv,
    const float* __restrict__ Wp,
    const float* __restrict__ W1, const float* __restrict__ pre_g, const float* __restrict__ pre_b, const float* __restrict__ b1,
    const float* __restrict__ W2,
    ushort_t* WqT, ushort_t* WkT, ushort_t* WvT, ushort_t* WpT, ushort_t* W1T, ushort_t* W2T,
    float* uq, float* bbq, float* uk, float* bbk, float* uv, float* bbv, float* b1p) {
  const int mb = blockIdx.x;
  const float *W, *g = nullptr, *bln = nullptr, *bias = nullptr;
  ushort_t* WT; float *u = nullptr, *bb = nullptr;
  int kin = 128, nout = 128, ob;
  if (mb < 4)       { W=Wq; g=qg; bln=qb;   bias=bq; WT=WqT; u=uq; bb=bbq; ob=mb*32; }
  else if (mb < 8)  { W=Wk; g=kg; bln=kbb;  bias=bk; WT=WkT; u=uk; bb=bbk; ob=(mb-4)*32; }
  else if (mb < 12) { W=Wv; g=vg; bln=vbb;  bias=bv; WT=WvT; u=uv; bb=bbv; ob=(mb-8)*32; }
  else if (mb < 16) { W=Wp; WT=WpT; ob=(mb-12)*32; }
  else if (mb < 24) { W=W1; g=pre_g; bln=pre_b; bias=b1; WT=W1T; bb=b1p; nout=256; ob=(mb-16)*32; }
  else              { W=W2; WT=W2T; kin=256; ob=(mb-24)*32; }
  const int t = threadIdx.x;
  const int oc = t & 31, ig = t >> 5;
  const int out = ob + oc;
  const int nper = kin >> 3;           // 16 or 32, divisible by 8
  float su = 0.f, sb = 0.f;
  for (int j0 = 0; j0 < nper; j0 += 8) {
    float wv8[8];
#pragma unroll
    for (int j = 0; j < 8; ++j)
      wv8[j] = W[(size_t)(ig * nper + j0 + j) * nout + out];
#pragma unroll
    for (int j = 0; j < 8; ++j) {
      const int in = ig * nper + j0 + j;
      const float wg = g ? g[in] * wv8[j] : wv8[j];
      WT[(size_t)out * kin + in] = f2bf(wg);
      su += wg;
      if (bln) sb += bln[in] * wv8[j];
    }
  }
  __shared__ float sU[8][32], sB[8][32];
  sU[ig][oc] = su; sB[ig][oc] = sb;
  __syncthreads();
  if (t < 32) {
    float tu = 0.f, tb = 0.f;
#pragma unroll
    for (int i = 0; i < 8; ++i) { tu += sU[i][t]; tb += sB[i][t]; }
    if (u)  u[ob + t] = tu;
    if (bb) bb[ob + t] = tb + (bias ? bias[ob + t] : 0.f);
  }
}

// ---------------------------------------------------------------------------
// proj: bf16 MFMA GEMM on RAW x (LN folded into epilogue).
// 64-position tiles (measured-best geometry): grid 840, 256 thr.
// ---------------------------------------------------------------------------
__global__ __launch_bounds__(256) void proj_mfma(
    const float* __restrict__ xq, const float* __restrict__ xk, const float* __restrict__ xv,
    const ushort_t* __restrict__ WqT, const ushort_t* __restrict__ WkT, const ushort_t* __restrict__ WvT,
    const float* __restrict__ uq, const float* __restrict__ uk, const float* __restrict__ uv,
    const float* __restrict__ bbq, const float* __restrict__ bbk, const float* __restrict__ bbv,
    ushort_t* __restrict__ Qh, ushort_t* __restrict__ Kh, ushort_t* __restrict__ Vt) {
  int blk = blockIdx.x;
  const float* x; const ushort_t* WT; const float* u; const float* bb;
  ushort_t* out; int S, ntile, vmode; float oscale;
  if (blk < 192)      { x=xq; WT=WqT; u=uq; bb=bbq; out=Qh; S=SQL; ntile=16; vmode=0; oscale=QSCALE; }
  else if (blk < 516) { blk-=192; x=xk; WT=WkT; u=uk; bb=bbk; out=Kh; S=SKL; ntile=27; vmode=0; oscale=1.f; }
  else                { blk-=516; x=xv; WT=WvT; u=uv; bb=bbv; out=Vt; S=SKL; ntile=27; vmode=1; oscale=1.f; }
  const int bn = blk / ntile;
  const int pos0 = (blk - bn * ntile) * 64;
  int valid = S - pos0; if (valid > 64) valid = 64;   // 64 or 16

  const int t = threadIdx.x;
  __shared__ ushort_t sX[64 * 128];
  __shared__ float sS1[16][64], sS2[16][64];
  __shared__ float sMu[64], sRs[64];

  {  // stage + stats: thread = (pos-quad 0..15, ch-group 0..15)
    const int posq = t & 15, chg = t >> 4;
    int lp4 = 4 * posq; if (lp4 >= valid) lp4 = valid - 4;  // clamp (dup writes benign)
    const float* xb = x + ((size_t)bn * 128 + chg * 8) * S + pos0 + lp4;
    float v[8][4];
#pragma unroll
    for (int i = 0; i < 8; ++i) {
      const float4 f = *((const float4*)(xb + (size_t)i * S));
      v[i][0] = f.x; v[i][1] = f.y; v[i][2] = f.z; v[i][3] = f.w;
    }
#pragma unroll
    for (int j = 0; j < 4; ++j) {
      float s1 = 0.f, s2 = 0.f;
#pragma unroll
      for (int i = 0; i < 8; ++i) { s1 += v[i][j]; s2 += v[i][j] * v[i][j]; }
      sS1[chg][lp4 + j] = s1; sS2[chg][lp4 + j] = s2;
    }
#pragma unroll
    for (int j = 0; j < 4; ++j) {
      const int pos = lp4 + j;
      short8 pk;
#pragma unroll
      for (int i = 0; i < 8; ++i) pk[i] = (short)f2bf(v[i][j]);
      const int phys = chg ^ (pos & 7);
      *((short8*)&sX[pos * 128 + phys * 8]) = pk;
    }
  }
  __syncthreads();
  if (t < 64) {
    float a1 = 0.f, a2 = 0.f;
#pragma unroll
    for (int g = 0; g < 16; ++g) { a1 += sS1[g][t]; a2 += sS2[g][t]; }
    const float mu = a1 * (1.f / 128.f);
    sMu[t] = mu; sRs[t] = rsqrtf(a2 * (1.f / 128.f) - mu * mu + 1e-5f);
  }
  __syncthreads();

  const int w = t >> 6, l = t & 63, lq = l & 15, quad = l >> 4;
  short8 af[2][4];
#pragma unroll
  for (int ms = 0; ms < 2; ++ms)
#pragma unroll
    for (int kk = 0; kk < 4; ++kk)
      af[ms][kk] = *((const short8*)(WT + (size_t)(w * 32 + ms * 16 + lq) * 128 + quad * 8 + kk * 32));
  f32x4 acc[4][2];
#pragma unroll
  for (int ns = 0; ns < 4; ++ns)
#pragma unroll
    for (int ms = 0; ms < 2; ++ms) acc[ns][ms] = (f32x4){0.f, 0.f, 0.f, 0.f};
#pragma unroll
  for (int ns = 0; ns < 4; ++ns) {
    short8 bf[4];
#pragma unroll
    for (int kk = 0; kk < 4; ++kk) {
      const int phys = (quad + 4 * kk) ^ (lq & 7);
      bf[kk] = *((const short8*)&sX[(ns * 16 + lq) * 128 + phys * 8]);
    }
#pragma unroll
    for (int ms = 0; ms < 2; ++ms) {
      f32x4 a = acc[ns][ms];
#pragma unroll
      for (int kk = 0; kk < 4; ++kk) a = MFMA16(af[ms][kk], bf[kk], a, 0, 0, 0);
      acc[ns][ms] = a;
    }
  }

  const int b_ = bn / NCAM, cam = bn - b_ * NCAM;
  const size_t slab = (size_t)((b_ * NHEAD + w) * NCAM + cam);
#pragma unroll
  for (int ms = 0; ms < 2; ++ms) {
    float uu[4], bv_[4];
#pragma unroll
    for (int r = 0; r < 4; ++r) {
      const int og = w * 32 + ms * 16 + quad * 4 + r;
      uu[r] = u[og]; bv_[r] = bb[og];
    }
#pragma unroll
    for (int ns = 0; ns < 4; ++ns) {
      const int p = ns * 16 + lq;
      if (p < valid) {
        const float mu = sMu[p], rs = sRs[p];
        float val[4];
#pragma unroll
        for (int r = 0; r < 4; ++r)
          val[r] = ((acc[ns][ms][r] - mu * uu[r]) * rs + bv_[r]) * oscale;
        if (vmode == 0) {
          ushort_t e0 = f2bf(val[0]), e1 = f2bf(val[1]), e2 = f2bf(val[2]), e3 = f2bf(val[3]);
          ushort_t* orow = out + (slab * S + pos0 + p) * 32 + ms * 16 + quad * 4;
          *((uint_t*)orow) = (uint_t)e0 | ((uint_t)e1 << 16);
          *((uint_t*)(orow + 2)) = (uint_t)e2 | ((uint_t)e3 << 16);
        } else {
#pragma unroll
          for (int r = 0; r < 4; ++r)
            out[(slab * 32 + ms * 16 + quad * 4 + r) * (size_t)SKL + pos0 + p] = f2bf(val[r]);
        }
      }
    }
  }
}

// ---------------------------------------------------------------------------
// MFMA flash attention, no-max softmax (exp2; scale folded into Q).
// Grid 256 (bm in low 3 bits -> XCD L2 locality), 512 thr = 8 waves.
// Wave w: cam-triple (w>>2), key-quarter (w&3), TWO Q frags (q0, q0+16).
// ZERO-LDS PV: MFMA contracts A-elem j with B-elem j per (quad,j) k-slot,
// so any permutation pi of the 32 k-slots is valid if applied to BOTH P and
// V. With pi(quad*8+j) = 16*(j>=4) + quad*4 + (j&3), each lane's PV B-frag
// is exactly the 8 exp2 values it already holds from QK's C/D layout
// (sA[st][r] = P[st*16 + quad*4 + r][lq]) -> P never touches LDS. V is
// loaded with the same pi via two 8B loads per frag (cols kb+q*4, kb+16+q*4).
// Replaces 8 ds_write_b64 + 4 ds_read_b128 + lgkm waits per wave-tile.
// Denominator shuffle hoisted out of the loop (2 shfl total, was 4/tile).
// LDS now only sO/sL for the final combine.
// ---------------------------------------------------------------------------
__global__ __launch_bounds__(512, 2) void attn_mfma(
    const ushort_t* __restrict__ Qh, const ushort_t* __restrict__ Kh,
    const ushort_t* __restrict__ Vt, ushort_t* __restrict__ Ab) {
  const int t = threadIdx.x;
  const int w = t >> 6, l = t & 63;
  const int lq = l & 15, quad = l >> 4;
  const int bm = blockIdx.x & 7;
  const int q0 = (blockIdx.x >> 3) * 32;
  const int camg = w >> 2, kq = w & 3;
  const int kstart = kq * 448;
  const int nfull = (kq == 3) ? 5 : 7;

  __shared__ __align__(16) unsigned char smem[74752];
  float (*sO)[2][16][36] = (float(*)[2][16][36])smem;       // 73,728 B
  float (*sL)[2][16] = (float(*)[2][16])(smem + 73728);     // 1,024 B

  f32x4 oA0 = {0.f,0.f,0.f,0.f}, oA1 = {0.f,0.f,0.f,0.f};
  f32x4 oB0 = {0.f,0.f,0.f,0.f}, oB1 = {0.f,0.f,0.f,0.f};
  float lA = 0.f, lB = 0.f;

  for (int nc = 0; nc < 3; ++nc) {
    const int n = camg * 3 + nc;
    const ushort_t* Kb = Kh + (size_t)(bm * NCAM + n) * SKL * 32;
    const ushort_t* Vb = Vt + (size_t)(bm * NCAM + n) * 32 * SKL;
    const ushort_t* Qbase = Qh + ((size_t)(bm * NCAM + n) * SQL + q0) * 32;
    const short8 qfA = *((const short8*)(Qbase + (size_t)lq * 32 + quad * 8));
    const short8 qfB = *((const short8*)(Qbase + (size_t)(16 + lq) * 32 + quad * 8));

    // prefetch K tile 0 of this camera
    short8 kc[4];
#pragma unroll
    for (int st = 0; st < 4; ++st)
      kc[st] = *((const short8*)(Kb + (size_t)(kstart + st * 16 + lq) * 32 + quad * 8));

    for (int kt = 0; kt < nfull; ++kt) {
      const int kb = kstart + kt * 64;
      const int vq = quad * 4;
      // V loads, permuted by pi: two 8B loads per 32-k fragment per row
      const ushort_t* vp0 = Vb + (size_t)lq * SKL + kb + vq;
      const ushort_t* vp1 = Vb + (size_t)(16 + lq) * SKL + kb + vq;
      const uint2 r00 = *((const uint2*)(vp0));
      const uint2 r01 = *((const uint2*)(vp0 + 16));
      const uint2 r02 = *((const uint2*)(vp0 + 32));
      const uint2 r03 = *((const uint2*)(vp0 + 48));
      const uint2 r10 = *((const uint2*)(vp1));
      const uint2 r11 = *((const uint2*)(vp1 + 16));
      const uint2 r12 = *((const uint2*)(vp1 + 32));
      const uint2 r13 = *((const uint2*)(vp1 + 48));
      uint4v c;
      c[0] = r00.x; c[1] = r00.y; c[2] = r01.x; c[3] = r01.y;
      const short8 v00 = __builtin_bit_cast(short8, c);
      c[0] = r02.x; c[1] = r02.y; c[2] = r03.x; c[3] = r03.y;
      const short8 v01 = __builtin_bit_cast(short8, c);
      c[0] = r10.x; c[1] = r10.y; c[2] = r11.x; c[3] = r11.y;
      const short8 v10 = __builtin_bit_cast(short8, c);
      c[0] = r12.x; c[1] = r12.y; c[2] = r13.x; c[3] = r13.y;
      const short8 v11 = __builtin_bit_cast(short8, c);
      // prefetch next tile's K (wave-uniform branch)
      short8 kn[4] = {kc[0], kc[1], kc[2], kc[3]};
      if (kt + 1 < nfull) {
        const int kbn = kb + 64;
#pragma unroll
        for (int st = 0; st < 4; ++st)
          kn[st] = *((const short8*)(Kb + (size_t)(kbn + st * 16 + lq) * 32 + quad * 8));
      }

      f32x4 sA[4], sB[4];
#pragma unroll
      for (int st = 0; st < 4; ++st) {
        f32x4 z = {0.f, 0.f, 0.f, 0.f};
        sA[st] = MFMA16(kc[st], qfA, z, 0, 0, 0);
        sB[st] = MFMA16(kc[st], qfB, z, 0, 0, 0);
      }
      float eA[4][4], eB[4][4];
#pragma unroll
      for (int st = 0; st < 4; ++st) {
#pragma unroll
        for (int r = 0; r < 4; ++r) {
          eA[st][r] = __builtin_amdgcn_exp2f(sA[st][r]);
          eB[st][r] = __builtin_amdgcn_exp2f(sB[st][r]);
        }
        lA += (eA[st][0] + eA[st][1]) + (eA[st][2] + eA[st][3]);
        lB += (eB[st][0] + eB[st][1]) + (eB[st][2] + eB[st][3]);
      }
      // pack P in-register: B-frag elem j = P[pi(quad*8+j)][lq] = own values
      uint4v pw;
      pw[0] = pk2(eA[0][0], eA[0][1]); pw[1] = pk2(eA[0][2], eA[0][3]);
      pw[2] = pk2(eA[1][0], eA[1][1]); pw[3] = pk2(eA[1][2], eA[1][3]);
      const short8 pfA0 = __builtin_bit_cast(short8, pw);
      pw[0] = pk2(eA[2][0], eA[2][1]); pw[1] = pk2(eA[2][2], eA[2][3]);
      pw[2] = pk2(eA[3][0], eA[3][1]); pw[3] = pk2(eA[3][2], eA[3][3]);
      const short8 pfA1 = __builtin_bit_cast(short8, pw);
      pw[0] = pk2(eB[0][0], eB[0][1]); pw[1] = pk2(eB[0][2], eB[0][3]);
      pw[2] = pk2(eB[1][0], eB[1][1]); pw[3] = pk2(eB[1][2], eB[1][3]);
      const short8 pfB0 = __builtin_bit_cast(short8, pw);
      pw[0] = pk2(eB[2][0], eB[2][1]); pw[1] = pk2(eB[2][2], eB[2][3]);
      pw[2] = pk2(eB[3][0], eB[3][1]); pw[3] = pk2(eB[3][2], eB[3][3]);
      const short8 pfB1 = __builtin_bit_cast(short8, pw);

      oA0 = MFMA16(v00, pfA0, oA0, 0, 0, 0);
      oA1 = MFMA16(v10, pfA0, oA1, 0, 0, 0);
      oB0 = MFMA16(v00, pfB0, oB0, 0, 0, 0);
      oB1 = MFMA16(v10, pfB0, oB1, 0, 0, 0);
      oA0 = MFMA16(v01, pfA1, oA0, 0, 0, 0);
      oA1 = MFMA16(v11, pfA1, oA1, 0, 0, 0);
      oB0 = MFMA16(v01, pfB1, oB0, 0, 0, 0);
      oB1 = MFMA16(v11, pfB1, oB1, 0, 0, 0);
#pragma unroll
      for (int st = 0; st < 4; ++st) kc[st] = kn[st];
    }

    if (kq == 3) {  // 16-key tail (keys 1664..1679): st0 only, rest zeroed
      const int kb = kstart + 320;
      const int vq = quad * 4;
      const short8 kf = *((const short8*)(Kb + (size_t)(kb + lq) * 32 + quad * 8));
      const uint2 r00 = *((const uint2*)(Vb + (size_t)lq * SKL + kb + vq));
      const uint2 r10 = *((const uint2*)(Vb + (size_t)(16 + lq) * SKL + kb + vq));
      uint4v c;
      c[0] = r00.x; c[1] = r00.y; c[2] = 0u; c[3] = 0u;
      const short8 v00 = __builtin_bit_cast(short8, c);
      c[0] = r10.x; c[1] = r10.y; c[2] = 0u; c[3] = 0u;
      const short8 v10 = __builtin_bit_cast(short8, c);
      f32x4 z = {0.f, 0.f, 0.f, 0.f};
      const f32x4 s0A = MFMA16(kf, qfA, z, 0, 0, 0);
      const f32x4 s0B = MFMA16(kf, qfB, z, 0, 0, 0);
      float eA[4], eB[4];
#pragma unroll
      for (int r = 0; r < 4; ++r) {
        eA[r] = __builtin_amdgcn_exp2f(s0A[r]);
        eB[r] = __builtin_amdgcn_exp2f(s0B[r]);
      }
      lA += (eA[0] + eA[1]) + (eA[2] + eA[3]);
      lB += (eB[0] + eB[1]) + (eB[2] + eB[3]);
      uint4v pw;
      pw[0] = pk2(eA[0], eA[1]); pw[1] = pk2(eA[2], eA[3]); pw[2] = 0u; pw[3] = 0u;
      const short8 pfA0 = __builtin_bit_cast(short8, pw);
      pw[0] = pk2(eB[0], eB[1]); pw[1] = pk2(eB[2], eB[3]); pw[2] = 0u; pw[3] = 0u;
      const short8 pfB0 = __builtin_bit_cast(short8, pw);
      oA0 = MFMA16(v00, pfA0, oA0, 0, 0, 0);
      oA1 = MFMA16(v10, pfA0, oA1, 0, 0, 0);
      oB0 = MFMA16(v00, pfB0, oB0, 0, 0, 0);
      oB1 = MFMA16(v10, pfB0, oB1, 0, 0, 0);
    }
  }

  // single end-of-loop denominator reduce across quads (was 4 shfl per tile)
  lA += __shfl_xor(lA, 16, 64);
  lA += __shfl_xor(lA, 32, 64);
  lB += __shfl_xor(lB, 16, 64);
  lB += __shfl_xor(lB, 32, 64);

  // no LDS used before here -> no barrier needed before the sO writes
  *((f32x4*)&sO[w][0][lq][quad * 4]) = oA0;
  *((f32x4*)&sO[w][0][lq][16 + quad * 4]) = oA1;
  *((f32x4*)&sO[w][1][lq][quad * 4]) = oB0;
  *((f32x4*)&sO[w][1][lq][16 + quad * 4]) = oB1;
  if (l < 16) { sL[w][0][l] = lA; sL[w][1][l] = lB; }
  __syncthreads();
  if (w < 2) {
    const int frag = w;
    float lf = 0.f;
    f32x4 a0 = {0.f, 0.f, 0.f, 0.f}, a1 = {0.f, 0.f, 0.f, 0.f};
#pragma unroll
    for (int ww = 0; ww < 8; ++ww) {
      lf += sL[ww][frag][lq];
      a0 += *((const f32x4*)&sO[ww][frag][lq][quad * 4]);
      a1 += *((const f32x4*)&sO[ww][frag][lq][16 + quad * 4]);
    }
    const float inv = 1.f / lf;
    const int b = bm >> 2, hm = bm & 3;
    ushort_t* op = Ab + ((size_t)b * SQL + q0 + frag * 16 + lq) * 128 + hm * 32 + quad * 4;
    ushort4 w0 = make_ushort4(f2bf(a0[0] * inv), f2bf(a0[1] * inv), f2bf(a0[2] * inv), f2bf(a0[3] * inv));
    ushort4 w1 = make_ushort4(f2bf(a1[0] * inv), f2bf(a1[1] * inv), f2bf(a1[2] * inv), f2bf(a1[3] * inv));
    *((ushort4*)op) = w0;
    *((ushort4*)(op + 16)) = w1;
  }
}

// ---------------------------------------------------------------------------
// post: a@Wp + skip -> preLN -> gelu(n@W1''+b1'')@W2 + res -> postLN -> out.
// 8-position tiles, grid 256. LN stats parallelized across all 256 threads
// (confirmed win, R4).
// ---------------------------------------------------------------------------
__global__ __launch_bounds__(256) void post_mfma(
    const ushort_t* __restrict__ Ab, const float* __restrict__ skip,
    const ushort_t* __restrict__ WpT, const float* __restrict__ bp,
    const float* __restrict__ pre_g, const float* __restrict__ pre_b,
    const ushort_t* __restrict__ W1T, const float* __restrict__ b1p,
    const ushort_t* __restrict__ W2T, const float* __restrict__ b2,
    const float* __restrict__ post_g, const float* __restrict__ post_b,
    float* __restrict__ out) {
  const int t = threadIdx.x;
  const int w = t >> 6, l = t & 63, lq = l & 15, quad = l >> 4;
  const int b = blockIdx.x >> 7;
  const int p0 = (blockIdx.x & 127) * 8;
  const int rp = (p0 + lq < SQL) ? (p0 + lq) : (SQL - 1);   // clamped row

  __shared__ float zf[16 * 132];
  __shared__ float sRes[16 * 132];
  __shared__ ushort_t sZb[16 * 128];
  __shared__ ushort_t sH[16 * 256];
  __shared__ float sMu[16], sRs[16];

  // ---- GEMM1: z = a@Wp ----
  f32x4 z[2] = {{0.f,0.f,0.f,0.f},{0.f,0.f,0.f,0.f}};
#pragma unroll
  for (int kk = 0; kk < 4; ++kk) {
    const short8 bfr = *((const short8*)(Ab + ((size_t)b * SQL + rp) * 128 + quad * 8 + kk * 32));
#pragma unroll
    for (int ms = 0; ms < 2; ++ms) {
      const short8 afr = *((const short8*)(WpT + (size_t)(w * 32 + ms * 16 + lq) * 128 + quad * 8 + kk * 32));
      z[ms] = MFMA16(afr, bfr, z[ms], 0, 0, 0);
    }
  }
#pragma unroll
  for (int ms = 0; ms < 2; ++ms)
#pragma unroll
    for (int r = 0; r < 4; ++r) {
      const int o = w * 32 + ms * 16 + quad * 4 + r;
      const int rr = (p0 + lq < SQL) ? (p0 + lq) : (SQL - 1);
      zf[lq * 132 + o] = z[ms][r] + bp[o] + skip[(size_t)b * 131072 + (size_t)o * 1024 + rr];
    }
  __syncthreads();
  {  // LN1 stats: all 256 threads; pos = t>>4, lane j = t&15 -> 8 channels each
    const int pos = t >> 4, j = t & 15;
    float s1 = 0.f, s2 = 0.f;
#pragma unroll
    for (int c = 0; c < 8; ++c) { const float vv = zf[pos * 132 + j * 8 + c]; s1 += vv; s2 += vv * vv; }
    s1 += __shfl_xor(s1, 1, 64); s1 += __shfl_xor(s1, 2, 64);
    s1 += __shfl_xor(s1, 4, 64); s1 += __shfl_xor(s1, 8, 64);
    s2 += __shfl_xor(s2, 1, 64); s2 += __shfl_xor(s2, 2, 64);
    s2 += __shfl_xor(s2, 4, 64); s2 += __shfl_xor(s2, 8, 64);
    if (j == 0) {
      const float mu = s1 * (1.f / 128.f);
      sMu[pos] = mu; sRs[pos] = rsqrtf(s2 * (1.f / 128.f) - mu * mu + 1e-5f);
    }
  }
  __syncthreads();
  {
    const int pos = t & 15, grp = t >> 4;
    const float mu = sMu[pos], rs = sRs[pos];
    short8 pk;
#pragma unroll
    for (int i = 0; i < 8; ++i) {
      const int ch = grp * 8 + i;
      const float nv = (zf[pos * 132 + ch] - mu) * rs;
      pk[i] = (short)f2bf(nv);
      sRes[pos * 132 + ch] = nv * pre_g[ch] + pre_b[ch];
    }
    *((short8*)&sZb[pos * 128 + (grp ^ (pos & 7)) * 8]) = pk;
  }
  __syncthreads();
  // ---- GEMM2 + gelu ----
  f32x4 h[4];
#pragma unroll
  for (int ms = 0; ms < 4; ++ms) h[ms] = (f32x4){0.f, 0.f, 0.f, 0.f};
  short8 bz[4];
#pragma unroll
  for (int kk = 0; kk < 4; ++kk)
    bz[kk] = *((const short8*)&sZb[lq * 128 + ((quad + 4 * kk) ^ (lq & 7)) * 8]);
#pragma unroll
  for (int ms = 0; ms < 4; ++ms)
#pragma unroll
    for (int kk = 0; kk < 4; ++kk) {
      const short8 afr = *((const short8*)(W1T + (size_t)(w * 64 + ms * 16 + lq) * 128 + quad * 8 + kk * 32));
      h[ms] = MFMA16(afr, bz[kk], h[ms], 0, 0, 0);
    }
#pragma unroll
  for (int ms = 0; ms < 4; ++ms)
#pragma unroll
    for (int r = 0; r < 4; ++r) {
      const int o = w * 64 + ms * 16 + quad * 4 + r;
      const float hv = fast_gelu(h[ms][r] + b1p[o]);
      const int phys = (o >> 3) ^ (lq & 7);
      sH[lq * 256 + phys * 8 + (o & 7)] = f2bf(hv);
    }
  __syncthreads();
  // ---- GEMM3 + residual ----
  f32x4 z2[2] = {{0.f,0.f,0.f,0.f},{0.f,0.f,0.f,0.f}};
#pragma unroll
  for (int kk = 0; kk < 8; ++kk) {
    const short8 bh = *((const short8*)&sH[lq * 256 + ((quad + 4 * kk) ^ (lq & 7)) * 8]);
#pragma unroll
    for (int ms = 0; ms < 2; ++ms) {
      const short8 afr = *((const short8*)(W2T + (size_t)(w * 32 + ms * 16 + lq) * 256 + quad * 8 + kk * 32));
      z2[ms] = MFMA16(afr, bh, z2[ms], 0, 0, 0);
    }
  }
  __syncthreads();
#pragma unroll
  for (int ms = 0; ms < 2; ++ms)
#pragma unroll
    for (int r = 0; r < 4; ++r) {
      const int o = w * 32 + ms * 16 + quad * 4 + r;
      zf[lq * 132 + o] = z2[ms][r] + b2[o] + sRes[lq * 132 + o];
    }
  __syncthreads();
  {  // LN2 stats: all 256 threads
    const int pos = t >> 4, j = t & 15;
    float s1 = 0.f, s2 = 0.f;
#pragma unroll
    for (int c = 0; c < 8; ++c) { const float vv = zf[pos * 132 + j * 8 + c]; s1 += vv; s2 += vv * vv; }
    s1 += __shfl_xor(s1, 1, 64); s1 += __shfl_xor(s1, 2, 64);
    s1 += __shfl_xor(s1, 4, 64); s1 += __shfl_xor(s1, 8, 64);
    s2 += __shfl_xor(s2, 1, 64); s2 += __shfl_xor(s2, 2, 64);
    s2 += __shfl_xor(s2, 4, 64); s2 += __shfl_xor(s2, 8, 64);
    if (j == 0) {
      const float mu = s1 * (1.f / 128.f);
      sMu[pos] = mu; sRs[pos] = rsqrtf(s2 * (1.f / 128.f) - mu * mu + 1e-5f);
    }
  }
  __syncthreads();
  {
    const int pos = t & 15, grp = t >> 4;
    if (pos < 8) {
      const float mu = sMu[pos], rs = sRs[pos];
#pragma unroll
      for (int i = 0; i < 8; ++i) {
        const int ch = grp * 8 + i;
        out[(size_t)b * 131072 + (size_t)ch * 1024 + p0 + pos] =
            (zf[pos * 132 + ch] - mu) * rs * post_g[ch] + post_b[ch];
      }
    }
  }
}

// ---------------------------------------------------------------------------
extern "C" void kernel_launch(void* const* d_in, const int* in_sizes, int n_in,
                              void* d_out, int out_size, void* d_ws, size_t ws_size,
                              hipStream_t stream) {
  const float* q_in   = (const float*)d_in[0];
  const float* k_in   = (const float*)d_in[1];
  const float* v_in   = (const float*)d_in[2];
  const float* skip   = (const float*)d_in[3];
  const float* q_ln_g = (const float*)d_in[4];
  const float* q_ln_b = (const float*)d_in[5];
  const float* Wq     = (const float*)d_in[6];
  const float* bq     = (const float*)d_in[7];
  const float* k_ln_g = (const float*)d_in[8];
  const float* k_ln_b = (const float*)d_in[9];
  const float* Wk     = (const float*)d_in[10];
  const float* bk     = (const float*)d_in[11];
  const float* v_ln_g = (const float*)d_in[12];
  const float* v_ln_b = (const float*)d_in[13];
  const float* Wv     = (const float*)d_in[14];
  const float* bv     = (const float*)d_in[15];
  const float* Wp     = (const float*)d_in[16];
  const float* bp     = (const float*)d_in[17];
  const float* pre_g  = (const float*)d_in[18];
  const float* pre_b  = (const float*)d_in[19];
  const float* W1     = (const float*)d_in[20];
  const float* b1     = (const float*)d_in[21];
  const float* W2     = (const float*)d_in[22];
  const float* b2     = (const float*)d_in[23];
  const float* post_g = (const float*)d_in[24];
  const float* post_b = (const float*)d_in[25];

  char* base = (char*)d_ws;
  ushort_t* WqT = (ushort_t*)base; base += 16384 * 2;
  ushort_t* WkT = (ushort_t*)base; base += 16384 * 2;
  ushort_t* WvT = (ushort_t*)base; base += 16384 * 2;
  ushort_t* WpT = (ushort_t*)base; base += 16384 * 2;
  ushort_t* W1T = (ushort_t*)base; base += 32768 * 2;
  ushort_t* W2T = (ushort_t*)base; base += 32768 * 2;
  float* uq  = (float*)base; base += 128 * 4;
  float* bbq = (float*)base; base += 128 * 4;
  float* uk  = (float*)base; base += 128 * 4;
  float* bbk = (float*)base; base += 128 * 4;
  float* uv  = (float*)base; base += 128 * 4;
  float* bbv = (float*)base; base += 128 * 4;
  float* b1p = (float*)base; base += 256 * 4;
  base = (char*)(((size_t)base + 255) & ~(size_t)255);
  ushort_t* Qh = (ushort_t*)base; base += (size_t)1572864 * 2;
  ushort_t* Kh = (ushort_t*)base; base += (size_t)(2580480 + 4096) * 2;
  ushort_t* Vt = (ushort_t*)base; base += (size_t)(2580480 + 4096) * 2;
  ushort_t* Ab = (ushort_t*)base; base += (size_t)262144 * 2;
  float* out = (float*)d_out;

  prep_kernel<<<28, 256, 0, stream>>>(
      Wq, q_ln_g, q_ln_b, bq, Wk, k_ln_g, k_ln_b, bk, Wv, v_ln_g, v_ln_b, bv,
      Wp, W1, pre_g, pre_b, b1, W2,
      WqT, WkT, WvT, WpT, W1T, W2T, uq, bbq, uk, bbk, uv, bbv, b1p);
  proj_mfma<<<840, 256, 0, stream>>>(
      q_in, k_in, v_in, WqT, WkT, WvT, uq, uk, uv, bbq, bbk, bbv, Qh, Kh, Vt);
  attn_mfma<<<256, 512, 0, stream>>>(Qh, Kh, Vt, Ab);
  post_mfma<<<256, 256, 0, stream>>>(
      Ab, skip, WpT, bp, pre_g, pre_b, W1T, b1p, W2T, b2, post_g, post_b, out);
}

// Round 6
// 165.260 us; speedup vs baseline: 1.0678x; 1.0678x over previous
//
#include <hip/hip_runtime.h>
#include <math.h>

#define NCAM 6
#define BSZ 2
#define SQL 1024
#define SKL 1680
#define SKLP 1696   // Vt row stride: SKL padded to multiple of 32 (tail block)
#define NHEAD 4
#define DHEAD 32
// 1/sqrt(32) * log2(e)  (folded into Q so softmax uses exp2 directly)
#define QSCALE 0.25503494f

typedef unsigned short ushort_t;
typedef unsigned int uint_t;
typedef __attribute__((ext_vector_type(8))) short short8;   // 8 bf16
typedef __attribute__((ext_vector_type(4))) float f32x4;    // MFMA C/D frag
typedef __attribute__((ext_vector_type(4))) uint_t uint4v;  // 4 packed bf16x2

#define MFMA16 __builtin_amdgcn_mfma_f32_16x16x32_bf16

__device__ __forceinline__ ushort_t f2bf(float x) {
  uint_t u = __builtin_bit_cast(uint_t, x);
  u += 0x7FFFu + ((u >> 16) & 1u);   // RNE
  return (ushort_t)(u >> 16);
}

// pack two f32 -> (bf16(e0) | bf16(e1)<<16), truncation (same numerics as prior rounds)
__device__ __forceinline__ uint_t pk2(float e0, float e1) {
  return __builtin_amdgcn_perm(__builtin_bit_cast(uint_t, e1), __builtin_bit_cast(uint_t, e0), 0x07060302u);
}

// exact-grade GELU: erf via Abramowitz-Stegun 7.1.26 (|err|<=1.5e-7)
__device__ __forceinline__ float fast_gelu(float x) {
  const float ax = fabsf(x) * 0.70710678118654752f;
  const float tt = __builtin_amdgcn_rcpf(fmaf(0.3275911f, ax, 1.f));
  float poly = fmaf(tt, 1.061405429f, -1.453152027f);
  poly = fmaf(tt, poly, 1.421413741f);
  poly = fmaf(tt, poly, -0.284496736f);
  poly = fmaf(tt, poly, 0.254829592f);
  poly *= tt;
  const float e = __builtin_amdgcn_exp2f(-ax * ax * 1.4426950408889634f);
  float er = fmaf(-poly, e, 1.f);
  er = copysignf(er, x);
  return 0.5f * x * (1.f + er);
}

// ---------------------------------------------------------------------------
// prep: fold LN gains into transposed bf16 weights.
// Loads batched 8-wide so 8 global loads are in flight (confirmed win, R4).
// ---------------------------------------------------------------------------
__global__ __launch_bounds__(256) void prep_kernel(
    const float* __restrict__ Wq, const float* __restrict__ qg, const float* __restrict__ qb, const float* __restrict__ bq,
    const float* __restrict__ Wk, const float* __restrict__ kg, const float* __restrict__ kbb, const float* __restrict__ bk,
    const float* __restrict__ Wv, const float* __restrict__ vg, const float* __restrict__ vbb, const float* __restrict__ bv,
    const float* __restrict__ Wp,
    const float* __restrict__ W1, const float* __restrict__ pre_g, const float* __restrict__ pre_b, const float* __restrict__ b1,
    const float* __restrict__ W2,
    ushort_t* WqT, ushort_t* WkT, ushort_t* WvT, ushort_t* WpT, ushort_t* W1T, ushort_t* W2T,
    float* uq, float* bbq, float* uk, float* bbk, float* uv, float* bbv, float* b1p) {
  const int mb = blockIdx.x;
  const float *W, *g = nullptr, *bln = nullptr, *bias = nullptr;
  ushort_t* WT; float *u = nullptr, *bb = nullptr;
  int kin = 128, nout = 128, ob;
  if (mb < 4)       { W=Wq; g=qg; bln=qb;   bias=bq; WT=WqT; u=uq; bb=bbq; ob=mb*32; }
  else if (mb < 8)  { W=Wk; g=kg; bln=kbb;  bias=bk; WT=WkT; u=uk; bb=bbk; ob=(mb-4)*32; }
  else if (mb < 12) { W=Wv; g=vg; bln=vbb;  bias=bv; WT=WvT; u=uv; bb=bbv; ob=(mb-8)*32; }
  else if (mb < 16) { W=Wp; WT=WpT; ob=(mb-12)*32; }
  else if (mb < 24) { W=W1; g=pre_g; bln=pre_b; bias=b1; WT=W1T; bb=b1p; nout=256; ob=(mb-16)*32; }
  else              { W=W2; WT=W2T; kin=256; ob=(mb-24)*32; }
  const int t = threadIdx.x;
  const int oc = t & 31, ig = t >> 5;
  const int out = ob + oc;
  const int nper = kin >> 3;           // 16 or 32, divisible by 8
  float su = 0.f, sb = 0.f;
  for (int j0 = 0; j0 < nper; j0 += 8) {
    float wv8[8];
#pragma unroll
    for (int j = 0; j < 8; ++j)
      wv8[j] = W[(size_t)(ig * nper + j0 + j) * nout + out];
#pragma unroll
    for (int j = 0; j < 8; ++j) {
      const int in = ig * nper + j0 + j;
      const float wg = g ? g[in] * wv8[j] : wv8[j];
      WT[(size_t)out * kin + in] = f2bf(wg);
      su += wg;
      if (bln) sb += bln[in] * wv8[j];
    }
  }
  __shared__ float sU[8][32], sB[8][32];
  sU[ig][oc] = su; sB[ig][oc] = sb;
  __syncthreads();
  if (t < 32) {
    float tu = 0.f, tb = 0.f;
#pragma unroll
    for (int i = 0; i < 8; ++i) { tu += sU[i][t]; tb += sB[i][t]; }
    if (u)  u[ob + t] = tu;
    if (bb) bb[ob + t] = tb + (bias ? bias[ob + t] : 0.f);
  }
}

// ---------------------------------------------------------------------------
// proj: bf16 MFMA GEMM on RAW x (LN folded into epilogue).
// 64-position tiles (measured-best geometry): grid 840, 256 thr.
// vmode==1 (V): store KEY-PERMUTED per 32-block (V'[d][b+s] = V[d][b+pi(s)],
// pi(s) = 16*((s&7)>=4) + (s>>3)*4 + (s&3)) with row stride SKLP=1696;
// phantom keys 1680..1695 zero-filled. This makes attn's zero-LDS PV A-frags
// plain contiguous 16B loads (same addresses as the R4 kernel).
// ---------------------------------------------------------------------------
__global__ __launch_bounds__(256) void proj_mfma(
    const float* __restrict__ xq, const float* __restrict__ xk, const float* __restrict__ xv,
    const ushort_t* __restrict__ WqT, const ushort_t* __restrict__ WkT, const ushort_t* __restrict__ WvT,
    const float* __restrict__ uq, const float* __restrict__ uk, const float* __restrict__ uv,
    const float* __restrict__ bbq, const float* __restrict__ bbk, const float* __restrict__ bbv,
    ushort_t* __restrict__ Qh, ushort_t* __restrict__ Kh, ushort_t* __restrict__ Vt) {
  int blk = blockIdx.x;
  const float* x; const ushort_t* WT; const float* u; const float* bb;
  ushort_t* out; int S, ntile, vmode; float oscale;
  if (blk < 192)      { x=xq; WT=WqT; u=uq; bb=bbq; out=Qh; S=SQL; ntile=16; vmode=0; oscale=QSCALE; }
  else if (blk < 516) { blk-=192; x=xk; WT=WkT; u=uk; bb=bbk; out=Kh; S=SKL; ntile=27; vmode=0; oscale=1.f; }
  else                { blk-=516; x=xv; WT=WvT; u=uv; bb=bbv; out=Vt; S=SKL; ntile=27; vmode=1; oscale=1.f; }
  const int bn = blk / ntile;
  const int pos0 = (blk - bn * ntile) * 64;
  int valid = S - pos0; if (valid > 64) valid = 64;   // 64 or 16

  const int t = threadIdx.x;
  __shared__ ushort_t sX[64 * 128];
  __shared__ float sS1[16][64], sS2[16][64];
  __shared__ float sMu[64], sRs[64];

  {  // stage + stats: thread = (pos-quad 0..15, ch-group 0..15)
    const int posq = t & 15, chg = t >> 4;
    int lp4 = 4 * posq; if (lp4 >= valid) lp4 = valid - 4;  // clamp (dup writes benign)
    const float* xb = x + ((size_t)bn * 128 + chg * 8) * S + pos0 + lp4;
    float v[8][4];
#pragma unroll
    for (int i = 0; i < 8; ++i) {
      const float4 f = *((const float4*)(xb + (size_t)i * S));
      v[i][0] = f.x; v[i][1] = f.y; v[i][2] = f.z; v[i][3] = f.w;
    }
#pragma unroll
    for (int j = 0; j < 4; ++j) {
      float s1 = 0.f, s2 = 0.f;
#pragma unroll
      for (int i = 0; i < 8; ++i) { s1 += v[i][j]; s2 += v[i][j] * v[i][j]; }
      sS1[chg][lp4 + j] = s1; sS2[chg][lp4 + j] = s2;
    }
#pragma unroll
    for (int j = 0; j < 4; ++j) {
      const int pos = lp4 + j;
      short8 pk;
#pragma unroll
      for (int i = 0; i < 8; ++i) pk[i] = (short)f2bf(v[i][j]);
      const int phys = chg ^ (pos & 7);
      *((short8*)&sX[pos * 128 + phys * 8]) = pk;
    }
  }
  __syncthreads();
  if (t < 64) {
    float a1 = 0.f, a2 = 0.f;
#pragma unroll
    for (int g = 0; g < 16; ++g) { a1 += sS1[g][t]; a2 += sS2[g][t]; }
    const float mu = a1 * (1.f / 128.f);
    sMu[t] = mu; sRs[t] = rsqrtf(a2 * (1.f / 128.f) - mu * mu + 1e-5f);
  }
  __syncthreads();

  const int w = t >> 6, l = t & 63, lq = l & 15, quad = l >> 4;
  short8 af[2][4];
#pragma unroll
  for (int ms = 0; ms < 2; ++ms)
#pragma unroll
    for (int kk = 0; kk < 4; ++kk)
      af[ms][kk] = *((const short8*)(WT + (size_t)(w * 32 + ms * 16 + lq) * 128 + quad * 8 + kk * 32));
  f32x4 acc[4][2];
#pragma unroll
  for (int ns = 0; ns < 4; ++ns)
#pragma unroll
    for (int ms = 0; ms < 2; ++ms) acc[ns][ms] = (f32x4){0.f, 0.f, 0.f, 0.f};
#pragma unroll
  for (int ns = 0; ns < 4; ++ns) {
    short8 bf[4];
#pragma unroll
    for (int kk = 0; kk < 4; ++kk) {
      const int phys = (quad + 4 * kk) ^ (lq & 7);
      bf[kk] = *((const short8*)&sX[(ns * 16 + lq) * 128 + phys * 8]);
    }
#pragma unroll
    for (int ms = 0; ms < 2; ++ms) {
      f32x4 a = acc[ns][ms];
#pragma unroll
      for (int kk = 0; kk < 4; ++kk) a = MFMA16(af[ms][kk], bf[kk], a, 0, 0, 0);
      acc[ns][ms] = a;
    }
  }

  const int b_ = bn / NCAM, cam = bn - b_ * NCAM;
  const size_t slab = (size_t)((b_ * NHEAD + w) * NCAM + cam);
#pragma unroll
  for (int ms = 0; ms < 2; ++ms) {
    float uu[4], bv_[4];
#pragma unroll
    for (int r = 0; r < 4; ++r) {
      const int og = w * 32 + ms * 16 + quad * 4 + r;
      uu[r] = u[og]; bv_[r] = bb[og];
    }
#pragma unroll
    for (int ns = 0; ns < 4; ++ns) {
      const int p = ns * 16 + lq;
      if (vmode == 0) {
        if (p < valid) {
          const float mu = sMu[p], rs = sRs[p];
          float val[4];
#pragma unroll
          for (int r = 0; r < 4; ++r)
            val[r] = ((acc[ns][ms][r] - mu * uu[r]) * rs + bv_[r]) * oscale;
          ushort_t e0 = f2bf(val[0]), e1 = f2bf(val[1]), e2 = f2bf(val[2]), e3 = f2bf(val[3]);
          ushort_t* orow = out + (slab * S + pos0 + p) * 32 + ms * 16 + quad * 4;
          *((uint_t*)orow) = (uint_t)e0 | ((uint_t)e1 << 16);
          *((uint_t*)(orow + 2)) = (uint_t)e2 | ((uint_t)e3 << 16);
        }
      } else {
        const int key = pos0 + p;
        if (key < SKLP) {   // includes zero-fill of phantom keys 1680..1695
          ushort_t wv[4] = {0, 0, 0, 0};
          if (p < valid) {
            const float mu = sMu[p], rs = sRs[p];
#pragma unroll
            for (int r = 0; r < 4; ++r)
              wv[r] = f2bf((acc[ns][ms][r] - mu * uu[r]) * rs + bv_[r]);
          }
          const int o = key & 31;
          const int col = (key & ~31) + ((o >> 2) & 3) * 8 + ((o >> 4) << 2) + (o & 3);
#pragma unroll
          for (int r = 0; r < 4; ++r)
            out[(slab * 32 + ms * 16 + quad * 4 + r) * (size_t)SKLP + col] = wv[r];
        }
      }
    }
  }
}

// ---------------------------------------------------------------------------
// MFMA flash attention, no-max softmax (exp2; scale folded into Q).
// Grid 256 (bm in low 3 bits -> XCD L2 locality), 512 thr = 8 waves.
// Wave w: cam-triple (w>>2), key-quarter (w&3), TWO Q frags (q0, q0+16).
// ZERO-LDS PV (v2): P stays in registers via the k-slot permutation pi
// applied to BOTH operands; V is PRE-PERMUTED in Vt by proj, so A-frags are
// contiguous 16B loads (same addresses/stride pattern as R4, stride SKLP).
// PHASE-SPLIT (st0/1 then st2/3) halves live exp2 state -> ~105 VGPR, no
// spills under the (512,2) 128-VGPR budget (R5's failure mode).
// Removes 8 ds_write + 4 ds_read + lgkm waits per wave-tile vs R4.
// LDS only sO/sL at the final combine.
// ---------------------------------------------------------------------------
__global__ __launch_bounds__(512, 2) void attn_mfma(
    const ushort_t* __restrict__ Qh, const ushort_t* __restrict__ Kh,
    const ushort_t* __restrict__ Vt, ushort_t* __restrict__ Ab) {
  const int t = threadIdx.x;
  const int w = t >> 6, l = t & 63;
  const int lq = l & 15, quad = l >> 4;
  const int bm = blockIdx.x & 7;
  const int q0 = (blockIdx.x >> 3) * 32;
  const int camg = w >> 2, kq = w & 3;
  const int kstart = kq * 448;
  const int nfull = (kq == 3) ? 5 : 7;

  __shared__ __align__(16) unsigned char smem[74752];
  float (*sO)[2][16][36] = (float(*)[2][16][36])smem;       // 73,728 B
  float (*sL)[2][16] = (float(*)[2][16])(smem + 73728);     // 1,024 B

  f32x4 oA0 = {0.f,0.f,0.f,0.f}, oA1 = {0.f,0.f,0.f,0.f};
  f32x4 oB0 = {0.f,0.f,0.f,0.f}, oB1 = {0.f,0.f,0.f,0.f};
  float lA = 0.f, lB = 0.f;

  for (int nc = 0; nc < 3; ++nc) {
    const int n = camg * 3 + nc;
    const ushort_t* Kb = Kh + (size_t)(bm * NCAM + n) * SKL * 32;
    const ushort_t* Vb = Vt + (size_t)(bm * NCAM + n) * 32 * SKLP;
    const ushort_t* Qbase = Qh + ((size_t)(bm * NCAM + n) * SQL + q0) * 32;
    const short8 qfA = *((const short8*)(Qbase + (size_t)lq * 32 + quad * 8));
    const short8 qfB = *((const short8*)(Qbase + (size_t)(16 + lq) * 32 + quad * 8));

    // prefetch K tile 0 of this camera
    short8 kc[4];
#pragma unroll
    for (int st = 0; st < 4; ++st)
      kc[st] = *((const short8*)(Kb + (size_t)(kstart + st * 16 + lq) * 32 + quad * 8));

    for (int kt = 0; kt < nfull; ++kt) {
      const int kb = kstart + kt * 64;
      // V loads: contiguous 16B (values pre-permuted by proj)
      const short8 v00 = *((const short8*)(Vb + (size_t)lq * SKLP + kb + quad * 8));
      const short8 v01 = *((const short8*)(Vb + (size_t)lq * SKLP + kb + 32 + quad * 8));
      const short8 v10 = *((const short8*)(Vb + (size_t)(16 + lq) * SKLP + kb + quad * 8));
      const short8 v11 = *((const short8*)(Vb + (size_t)(16 + lq) * SKLP + kb + 32 + quad * 8));
      // prefetch next tile's K (wave-uniform branch)
      short8 kn[4] = {kc[0], kc[1], kc[2], kc[3]};
      if (kt + 1 < nfull) {
        const int kbn = kb + 64;
#pragma unroll
        for (int st = 0; st < 4; ++st)
          kn[st] = *((const short8*)(Kb + (size_t)(kbn + st * 16 + lq) * 32 + quad * 8));
      }

      const f32x4 zz = {0.f, 0.f, 0.f, 0.f};
      // ---- phase 1: k-slots of st 0,1 -> PV with v00,v10 ----
      {
        const f32x4 s0A = MFMA16(kc[0], qfA, zz, 0, 0, 0);
        const f32x4 s1A = MFMA16(kc[1], qfA, zz, 0, 0, 0);
        const f32x4 s0B = MFMA16(kc[0], qfB, zz, 0, 0, 0);
        const f32x4 s1B = MFMA16(kc[1], qfB, zz, 0, 0, 0);
        float e0A[4], e1A[4], e0B[4], e1B[4];
#pragma unroll
        for (int r = 0; r < 4; ++r) {
          e0A[r] = __builtin_amdgcn_exp2f(s0A[r]);
          e1A[r] = __builtin_amdgcn_exp2f(s1A[r]);
          e0B[r] = __builtin_amdgcn_exp2f(s0B[r]);
          e1B[r] = __builtin_amdgcn_exp2f(s1B[r]);
        }
        lA += ((e0A[0] + e0A[1]) + (e0A[2] + e0A[3])) + ((e1A[0] + e1A[1]) + (e1A[2] + e1A[3]));
        lB += ((e0B[0] + e0B[1]) + (e0B[2] + e0B[3])) + ((e1B[0] + e1B[1]) + (e1B[2] + e1B[3]));
        uint4v pw;
        pw[0] = pk2(e0A[0], e0A[1]); pw[1] = pk2(e0A[2], e0A[3]);
        pw[2] = pk2(e1A[0], e1A[1]); pw[3] = pk2(e1A[2], e1A[3]);
        const short8 pfA0 = __builtin_bit_cast(short8, pw);
        pw[0] = pk2(e0B[0], e0B[1]); pw[1] = pk2(e0B[2], e0B[3]);
        pw[2] = pk2(e1B[0], e1B[1]); pw[3] = pk2(e1B[2], e1B[3]);
        const short8 pfB0 = __builtin_bit_cast(short8, pw);
        oA0 = MFMA16(v00, pfA0, oA0, 0, 0, 0);
        oA1 = MFMA16(v10, pfA0, oA1, 0, 0, 0);
        oB0 = MFMA16(v00, pfB0, oB0, 0, 0, 0);
        oB1 = MFMA16(v10, pfB0, oB1, 0, 0, 0);
      }
      // ---- phase 2: k-slots of st 2,3 -> PV with v01,v11 ----
      {
        const f32x4 s2A = MFMA16(kc[2], qfA, zz, 0, 0, 0);
        const f32x4 s3A = MFMA16(kc[3], qfA, zz, 0, 0, 0);
        const f32x4 s2B = MFMA16(kc[2], qfB, zz, 0, 0, 0);
        const f32x4 s3B = MFMA16(kc[3], qfB, zz, 0, 0, 0);
        float e2A[4], e3A[4], e2B[4], e3B[4];
#pragma unroll
        for (int r = 0; r < 4; ++r) {
          e2A[r] = __builtin_amdgcn_exp2f(s2A[r]);
          e3A[r] = __builtin_amdgcn_exp2f(s3A[r]);
          e2B[r] = __builtin_amdgcn_exp2f(s2B[r]);
          e3B[r] = __builtin_amdgcn_exp2f(s3B[r]);
        }
        lA += ((e2A[0] + e2A[1]) + (e2A[2] + e2A[3])) + ((e3A[0] + e3A[1]) + (e3A[2] + e3A[3]));
        lB += ((e2B[0] + e2B[1]) + (e2B[2] + e2B[3])) + ((e3B[0] + e3B[1]) + (e3B[2] + e3B[3]));
        uint4v pw;
        pw[0] = pk2(e2A[0], e2A[1]); pw[1] = pk2(e2A[2], e2A[3]);
        pw[2] = pk2(e3A[0], e3A[1]); pw[3] = pk2(e3A[2], e3A[3]);
        const short8 pfA1 = __builtin_bit_cast(short8, pw);
        pw[0] = pk2(e2B[0], e2B[1]); pw[1] = pk2(e2B[2], e2B[3]);
        pw[2] = pk2(e3B[0], e3B[1]); pw[3] = pk2(e3B[2], e3B[3]);
        const short8 pfB1 = __builtin_bit_cast(short8, pw);
        oA0 = MFMA16(v01, pfA1, oA0, 0, 0, 0);
        oA1 = MFMA16(v11, pfA1, oA1, 0, 0, 0);
        oB0 = MFMA16(v01, pfB1, oB0, 0, 0, 0);
        oB1 = MFMA16(v11, pfB1, oB1, 0, 0, 0);
      }
#pragma unroll
      for (int st = 0; st < 4; ++st) kc[st] = kn[st];
    }

    if (kq == 3) {  // 16-key tail (keys 1664..1679); V' phantom slots are zero
      const int kb = kstart + 320;
      const short8 kf = *((const short8*)(Kb + (size_t)(kb + lq) * 32 + quad * 8));
      const short8 v00 = *((const short8*)(Vb + (size_t)lq * SKLP + kb + quad * 8));
      const short8 v10 = *((const short8*)(Vb + (size_t)(16 + lq) * SKLP + kb + quad * 8));
      const f32x4 zz = {0.f, 0.f, 0.f, 0.f};
      const f32x4 s0A = MFMA16(kf, qfA, zz, 0, 0, 0);
      const f32x4 s0B = MFMA16(kf, qfB, zz, 0, 0, 0);
      float eA[4], eB[4];
#pragma unroll
      for (int r = 0; r < 4; ++r) {
        eA[r] = __builtin_amdgcn_exp2f(s0A[r]);
        eB[r] = __builtin_amdgcn_exp2f(s0B[r]);
      }
      lA += (eA[0] + eA[1]) + (eA[2] + eA[3]);
      lB += (eB[0] + eB[1]) + (eB[2] + eB[3]);
      uint4v pw;
      pw[0] = pk2(eA[0], eA[1]); pw[1] = pk2(eA[2], eA[3]); pw[2] = 0u; pw[3] = 0u;
      const short8 pfA0 = __builtin_bit_cast(short8, pw);
      pw[0] = pk2(eB[0], eB[1]); pw[1] = pk2(eB[2], eB[3]); pw[2] = 0u; pw[3] = 0u;
      const short8 pfB0 = __builtin_bit_cast(short8, pw);
      oA0 = MFMA16(v00, pfA0, oA0, 0, 0, 0);
      oA1 = MFMA16(v10, pfA0, oA1, 0, 0, 0);
      oB0 = MFMA16(v00, pfB0, oB0, 0, 0, 0);
      oB1 = MFMA16(v10, pfB0, oB1, 0, 0, 0);
    }
  }

  // single end-of-loop denominator reduce across quads
  lA += __shfl_xor(lA, 16, 64);
  lA += __shfl_xor(lA, 32, 64);
  lB += __shfl_xor(lB, 16, 64);
  lB += __shfl_xor(lB, 32, 64);

  // no LDS used before here -> no barrier needed before the sO writes
  *((f32x4*)&sO[w][0][lq][quad * 4]) = oA0;
  *((f32x4*)&sO[w][0][lq][16 + quad * 4]) = oA1;
  *((f32x4*)&sO[w][1][lq][quad * 4]) = oB0;
  *((f32x4*)&sO[w][1][lq][16 + quad * 4]) = oB1;
  if (l < 16) { sL[w][0][l] = lA; sL[w][1][l] = lB; }
  __syncthreads();
  if (w < 2) {
    const int frag = w;
    float lf = 0.f;
    f32x4 a0 = {0.f, 0.f, 0.f, 0.f}, a1 = {0.f, 0.f, 0.f, 0.f};
#pragma unroll
    for (int ww = 0; ww < 8; ++ww) {
      lf += sL[ww][frag][lq];
      a0 += *((const f32x4*)&sO[ww][frag][lq][quad * 4]);
      a1 += *((const f32x4*)&sO[ww][frag][lq][16 + quad * 4]);
    }
    const float inv = 1.f / lf;
    const int b = bm >> 2, hm = bm & 3;
    ushort_t* op = Ab + ((size_t)b * SQL + q0 + frag * 16 + lq) * 128 + hm * 32 + quad * 4;
    ushort4 w0 = make_ushort4(f2bf(a0[0] * inv), f2bf(a0[1] * inv), f2bf(a0[2] * inv), f2bf(a0[3] * inv));
    ushort4 w1 = make_ushort4(f2bf(a1[0] * inv), f2bf(a1[1] * inv), f2bf(a1[2] * inv), f2bf(a1[3] * inv));
    *((ushort4*)op) = w0;
    *((ushort4*)(op + 16)) = w1;
  }
}

// ---------------------------------------------------------------------------
// post: a@Wp + skip -> preLN -> gelu(n@W1''+b1'')@W2 + res -> postLN -> out.
// 8-position tiles, grid 256. LN stats parallelized across all 256 threads
// (confirmed win, R4).
// ---------------------------------------------------------------------------
__global__ __launch_bounds__(256) void post_mfma(
    const ushort_t* __restrict__ Ab, const float* __restrict__ skip,
    const ushort_t* __restrict__ WpT, const float* __restrict__ bp,
    const float* __restrict__ pre_g, const float* __restrict__ pre_b,
    const ushort_t* __restrict__ W1T, const float* __restrict__ b1p,
    const ushort_t* __restrict__ W2T, const float* __restrict__ b2,
    const float* __restrict__ post_g, const float* __restrict__ post_b,
    float* __restrict__ out) {
  const int t = threadIdx.x;
  const int w = t >> 6, l = t & 63, lq = l & 15, quad = l >> 4;
  const int b = blockIdx.x >> 7;
  const int p0 = (blockIdx.x & 127) * 8;
  const int rp = (p0 + lq < SQL) ? (p0 + lq) : (SQL - 1);   // clamped row

  __shared__ float zf[16 * 132];
  __shared__ float sRes[16 * 132];
  __shared__ ushort_t sZb[16 * 128];
  __shared__ ushort_t sH[16 * 256];
  __shared__ float sMu[16], sRs[16];

  // ---- GEMM1: z = a@Wp ----
  f32x4 z[2] = {{0.f,0.f,0.f,0.f},{0.f,0.f,0.f,0.f}};
#pragma unroll
  for (int kk = 0; kk < 4; ++kk) {
    const short8 bfr = *((const short8*)(Ab + ((size_t)b * SQL + rp) * 128 + quad * 8 + kk * 32));
#pragma unroll
    for (int ms = 0; ms < 2; ++ms) {
      const short8 afr = *((const short8*)(WpT + (size_t)(w * 32 + ms * 16 + lq) * 128 + quad * 8 + kk * 32));
      z[ms] = MFMA16(afr, bfr, z[ms], 0, 0, 0);
    }
  }
#pragma unroll
  for (int ms = 0; ms < 2; ++ms)
#pragma unroll
    for (int r = 0; r < 4; ++r) {
      const int o = w * 32 + ms * 16 + quad * 4 + r;
      const int rr = (p0 + lq < SQL) ? (p0 + lq) : (SQL - 1);
      zf[lq * 132 + o] = z[ms][r] + bp[o] + skip[(size_t)b * 131072 + (size_t)o * 1024 + rr];
    }
  __syncthreads();
  {  // LN1 stats: all 256 threads; pos = t>>4, lane j = t&15 -> 8 channels each
    const int pos = t >> 4, j = t & 15;
    float s1 = 0.f, s2 = 0.f;
#pragma unroll
    for (int c = 0; c < 8; ++c) { const float vv = zf[pos * 132 + j * 8 + c]; s1 += vv; s2 += vv * vv; }
    s1 += __shfl_xor(s1, 1, 64); s1 += __shfl_xor(s1, 2, 64);
    s1 += __shfl_xor(s1, 4, 64); s1 += __shfl_xor(s1, 8, 64);
    s2 += __shfl_xor(s2, 1, 64); s2 += __shfl_xor(s2, 2, 64);
    s2 += __shfl_xor(s2, 4, 64); s2 += __shfl_xor(s2, 8, 64);
    if (j == 0) {
      const float mu = s1 * (1.f / 128.f);
      sMu[pos] = mu; sRs[pos] = rsqrtf(s2 * (1.f / 128.f) - mu * mu + 1e-5f);
    }
  }
  __syncthreads();
  {
    const int pos = t & 15, grp = t >> 4;
    const float mu = sMu[pos], rs = sRs[pos];
    short8 pk;
#pragma unroll
    for (int i = 0; i < 8; ++i) {
      const int ch = grp * 8 + i;
      const float nv = (zf[pos * 132 + ch] - mu) * rs;
      pk[i] = (short)f2bf(nv);
      sRes[pos * 132 + ch] = nv * pre_g[ch] + pre_b[ch];
    }
    *((short8*)&sZb[pos * 128 + (grp ^ (pos & 7)) * 8]) = pk;
  }
  __syncthreads();
  // ---- GEMM2 + gelu ----
  f32x4 h[4];
#pragma unroll
  for (int ms = 0; ms < 4; ++ms) h[ms] = (f32x4){0.f, 0.f, 0.f, 0.f};
  short8 bz[4];
#pragma unroll
  for (int kk = 0; kk < 4; ++kk)
    bz[kk] = *((const short8*)&sZb[lq * 128 + ((quad + 4 * kk) ^ (lq & 7)) * 8]);
#pragma unroll
  for (int ms = 0; ms < 4; ++ms)
#pragma unroll
    for (int kk = 0; kk < 4; ++kk) {
      const short8 afr = *((const short8*)(W1T + (size_t)(w * 64 + ms * 16 + lq) * 128 + quad * 8 + kk * 32));
      h[ms] = MFMA16(afr, bz[kk], h[ms], 0, 0, 0);
    }
#pragma unroll
  for (int ms = 0; ms < 4; ++ms)
#pragma unroll
    for (int r = 0; r < 4; ++r) {
      const int o = w * 64 + ms * 16 + quad * 4 + r;
      const float hv = fast_gelu(h[ms][r] + b1p[o]);
      const int phys = (o >> 3) ^ (lq & 7);
      sH[lq * 256 + phys * 8 + (o & 7)] = f2bf(hv);
    }
  __syncthreads();
  // ---- GEMM3 + residual ----
  f32x4 z2[2] = {{0.f,0.f,0.f,0.f},{0.f,0.f,0.f,0.f}};
#pragma unroll
  for (int kk = 0; kk < 8; ++kk) {
    const short8 bh = *((const short8*)&sH[lq * 256 + ((quad + 4 * kk) ^ (lq & 7)) * 8]);
#pragma unroll
    for (int ms = 0; ms < 2; ++ms) {
      const short8 afr = *((const short8*)(W2T + (size_t)(w * 32 + ms * 16 + lq) * 256 + quad * 8 + kk * 32));
      z2[ms] = MFMA16(afr, bh, z2[ms], 0, 0, 0);
    }
  }
  __syncthreads();
#pragma unroll
  for (int ms = 0; ms < 2; ++ms)
#pragma unroll
    for (int r = 0; r < 4; ++r) {
      const int o = w * 32 + ms * 16 + quad * 4 + r;
      zf[lq * 132 + o] = z2[ms][r] + b2[o] + sRes[lq * 132 + o];
    }
  __syncthreads();
  {  // LN2 stats: all 256 threads
    const int pos = t >> 4, j = t & 15;
    float s1 = 0.f, s2 = 0.f;
#pragma unroll
    for (int c = 0; c < 8; ++c) { const float vv = zf[pos * 132 + j * 8 + c]; s1 += vv; s2 += vv * vv; }
    s1 += __shfl_xor(s1, 1, 64); s1 += __shfl_xor(s1, 2, 64);
    s1 += __shfl_xor(s1, 4, 64); s1 += __shfl_xor(s1, 8, 64);
    s2 += __shfl_xor(s2, 1, 64); s2 += __shfl_xor(s2, 2, 64);
    s2 += __shfl_xor(s2, 4, 64); s2 += __shfl_xor(s2, 8, 64);
    if (j == 0) {
      const float mu = s1 * (1.f / 128.f);
      sMu[pos] = mu; sRs[pos] = rsqrtf(s2 * (1.f / 128.f) - mu * mu + 1e-5f);
    }
  }
  __syncthreads();
  {
    const int pos = t & 15, grp = t >> 4;
    if (pos < 8) {
      const float mu = sMu[pos], rs = sRs[pos];
#pragma unroll
      for (int i = 0; i < 8; ++i) {
        const int ch = grp * 8 + i;
        out[(size_t)b * 131072 + (size_t)ch * 1024 + p0 + pos] =
            (zf[pos * 132 + ch] - mu) * rs * post_g[ch] + post_b[ch];
      }
    }
  }
}

// ---------------------------------------------------------------------------
extern "C" void kernel_launch(void* const* d_in, const int* in_sizes, int n_in,
                              void* d_out, int out_size, void* d_ws, size_t ws_size,
                              hipStream_t stream) {
  const float* q_in   = (const float*)d_in[0];
  const float* k_in   = (const float*)d_in[1];
  const float* v_in   = (const float*)d_in[2];
  const float* skip   = (const float*)d_in[3];
  const float* q_ln_g = (const float*)d_in[4];
  const float* q_ln_b = (const float*)d_in[5];
  const float* Wq     = (const float*)d_in[6];
  const float* bq     = (const float*)d_in[7];
  const float* k_ln_g = (const float*)d_in[8];
  const float* k_ln_b = (const float*)d_in[9];
  const float* Wk     = (const float*)d_in[10];
  const float* bk     = (const float*)d_in[11];
  const float* v_ln_g = (const float*)d_in[12];
  const float* v_ln_b = (const float*)d_in[13];
  const float* Wv     = (const float*)d_in[14];
  const float* bv     = (const float*)d_in[15];
  const float* Wp     = (const float*)d_in[16];
  const float* bp     = (const float*)d_in[17];
  const float* pre_g  = (const float*)d_in[18];
  const float* pre_b  = (const float*)d_in[19];
  const float* W1     = (const float*)d_in[20];
  const float* b1     = (const float*)d_in[21];
  const float* W2     = (const float*)d_in[22];
  const float* b2     = (const float*)d_in[23];
  const float* post_g = (const float*)d_in[24];
  const float* post_b = (const float*)d_in[25];

  char* base = (char*)d_ws;
  ushort_t* WqT = (ushort_t*)base; base += 16384 * 2;
  ushort_t* WkT = (ushort_t*)base; base += 16384 * 2;
  ushort_t* WvT = (ushort_t*)base; base += 16384 * 2;
  ushort_t* WpT = (ushort_t*)base; base += 16384 * 2;
  ushort_t* W1T = (ushort_t*)base; base += 32768 * 2;
  ushort_t* W2T = (ushort_t*)base; base += 32768 * 2;
  float* uq  = (float*)base; base += 128 * 4;
  float* bbq = (float*)base; base += 128 * 4;
  float* uk  = (float*)base; base += 128 * 4;
  float* bbk = (float*)base; base += 128 * 4;
  float* uv  = (float*)base; base += 128 * 4;
  float* bbv = (float*)base; base += 128 * 4;
  float* b1p = (float*)base; base += 256 * 4;
  base = (char*)(((size_t)base + 255) & ~(size_t)255);
  ushort_t* Qh = (ushort_t*)base; base += (size_t)1572864 * 2;
  ushort_t* Kh = (ushort_t*)base; base += (size_t)(2580480 + 4096) * 2;
  // Vt: 48 slabs x 32 rows x SKLP(1696) cols = 2,605,056 ushorts (+ margin)
  ushort_t* Vt = (ushort_t*)base; base += (size_t)(2605056 + 4096) * 2;
  ushort_t* Ab = (ushort_t*)base; base += (size_t)262144 * 2;
  float* out = (float*)d_out;

  prep_kernel<<<28, 256, 0, stream>>>(
      Wq, q_ln_g, q_ln_b, bq, Wk, k_ln_g, k_ln_b, bk, Wv, v_ln_g, v_ln_b, bv,
      Wp, W1, pre_g, pre_b, b1, W2,
      WqT, WkT, WvT, WpT, W1T, W2T, uq, bbq, uk, bbk, uv, bbv, b1p);
  proj_mfma<<<840, 256, 0, stream>>>(
      q_in, k_in, v_in, WqT, WkT, WvT, uq, uk, uv, bbq, bbk, bbv, Qh, Kh, Vt);
  attn_mfma<<<256, 512, 0, stream>>>(Qh, Kh, Vt, Ab);
  post_mfma<<<256, 256, 0, stream>>>(
      Ab, skip, WpT, bp, pre_g, pre_b, W1T, b1p, W2T, b2, post_g, post_b, out);
}